// Round 1
// baseline (317.904 us; speedup 1.0000x reference)
//
#include <hip/hip_runtime.h>

// Problem constants (B=2, L=2048, D=1024, H=8, pd=128), fp32 throughout.
#define L_SEQ   2048
#define D_MODEL 1024
#define B_SZ    2
#define LP      (L_SEQ + 192)   // padded sequence length: 96 front + 96 back
#define PADF    96

// ---------------------------------------------------------------------------
// zero_pads: zero the 4 pad regions of vpad [B][LP][D].
// 4 regions x 96 rows x 1024 floats; one block zeroes one row (256 x float4).
__global__ __launch_bounds__(256) void zero_pads(float* __restrict__ vpad)
{
    const int r  = blockIdx.x / 96;       // region 0..3 = (b, front/back)
    const int rr = blockIdx.x % 96;       // row within region
    const int b  = r >> 1;
    const int row0 = (r & 1) ? (LP - 96) : 0;
    size_t off = ((size_t)b * LP + row0 + rr) * D_MODEL + threadIdx.x * 4;
    *(float4*)(vpad + off) = make_float4(0.f, 0.f, 0.f, 0.f);
}

// ---------------------------------------------------------------------------
// gemm_nt: C[M,N] = A[M,K] * B[N,K]^T,  M=4096, N=K=1024, fp32 vector ALU.
// Block tile 128(M) x 64(N), BK=16, 256 threads, 8x4 per-thread tile.
// DO_PAD=1 remaps output row m -> vpad row (b*LP + (m%L) + PADF).
template<int DO_PAD>
__global__ __launch_bounds__(256) void gemm_nt(const float* __restrict__ A,
                                               const float* __restrict__ Bw,
                                               float* __restrict__ C)
{
    __shared__ float As[16][132];   // k-major, pad 132 -> 2-way write conflict (free)
    __shared__ float Bs[16][68];

    const int tid = threadIdx.x;
    const int bm  = blockIdx.y * 128;
    const int bn  = blockIdx.x * 64;
    const int tm  = (tid >> 4) * 8;   // 0..120
    const int tn  = (tid & 15) * 4;   // 0..60

    // staging map: arow = tid/4 (row), akc = (tid%4)*4 (k-chunk)
    const int arow = tid >> 2;
    const int akc  = (tid & 3) << 2;
    const float* Ap0 = A  + (size_t)(bm + arow) * 1024 + akc;
    const float* Ap1 = Ap0 + (size_t)64 * 1024;
    const float* Bp  = Bw + (size_t)(bn + arow) * 1024 + akc;

    float acc[8][4];
    #pragma unroll
    for (int i = 0; i < 8; ++i)
        #pragma unroll
        for (int j = 0; j < 4; ++j) acc[i][j] = 0.f;

    for (int kt = 0; kt < 1024; kt += 16) {
        float4 a0 = *(const float4*)(Ap0 + kt);
        float4 a1 = *(const float4*)(Ap1 + kt);
        float4 b0 = *(const float4*)(Bp  + kt);
        __syncthreads();                       // previous tile fully consumed
        As[akc+0][arow]    = a0.x; As[akc+1][arow]    = a0.y;
        As[akc+2][arow]    = a0.z; As[akc+3][arow]    = a0.w;
        As[akc+0][arow+64] = a1.x; As[akc+1][arow+64] = a1.y;
        As[akc+2][arow+64] = a1.z; As[akc+3][arow+64] = a1.w;
        Bs[akc+0][arow]    = b0.x; Bs[akc+1][arow]    = b0.y;
        Bs[akc+2][arow]    = b0.z; Bs[akc+3][arow]    = b0.w;
        __syncthreads();
        #pragma unroll
        for (int k = 0; k < 16; ++k) {
            float4 av0 = *(const float4*)&As[k][tm];
            float4 av1 = *(const float4*)&As[k][tm + 4];
            float4 bv  = *(const float4*)&Bs[k][tn];
            float a[8] = {av0.x, av0.y, av0.z, av0.w, av1.x, av1.y, av1.z, av1.w};
            float b[4] = {bv.x, bv.y, bv.z, bv.w};
            #pragma unroll
            for (int i = 0; i < 8; ++i)
                #pragma unroll
                for (int j = 0; j < 4; ++j)
                    acc[i][j] = fmaf(a[i], b[j], acc[i][j]);
        }
    }

    #pragma unroll
    for (int i = 0; i < 8; ++i) {
        const int m = bm + tm + i;
        const size_t row = DO_PAD ? ((size_t)(m >> 11) * LP + (m & (L_SEQ - 1)) + PADF)
                                  : (size_t)m;
        float4 v = make_float4(acc[i][0], acc[i][1], acc[i][2], acc[i][3]);
        *(float4*)(C + row * 1024 + bn + tn) = v;
    }
}

// ---------------------------------------------------------------------------
// gauss_conv: att[b,q,d] = sum_delta w[h(d)][delta] * vpad[b, q+delta, d]
// delta window [-72, 56] (|dist| <= 8*sigma for every head; off_h = -sigma_h).
// Per thread: one d-column, 16 q accumulators; delta chunked by 16 with a
// 31-float register window so every FMA has static register indices.
__global__ __launch_bounds__(256) void gauss_conv(const float* __restrict__ vpad,
                                                  float* __restrict__ att)
{
    __shared__ float wt[8 * 160];   // head-major; index = h*160 + (delta + 87)
    const int tid = threadIdx.x;
    for (int i = tid; i < 8 * 160; i += 256) {
        const int h   = i / 160;
        const int dlt = (i % 160) - 87;
        const float sig = (float)(1 << (h & 3));   // std 1,2,4,8 ; offset = -std
        const float t = ((float)dlt + sig) / sig;
        wt[i] = (0.39894228040143267794f / sig) * expf(-0.5f * t * t);
    }
    __syncthreads();

    const int d  = blockIdx.x * 256 + tid;          // 0..1023
    const int q0 = blockIdx.y * 16;                 // 0..2032
    const int b  = blockIdx.z;
    const float* wrow = &wt[(d >> 7) * 160];        // wave-uniform (64 lanes in 1 head)
    const float* vb = vpad + ((size_t)b * LP + PADF + q0) * D_MODEL + d;

    float acc[16];
    #pragma unroll
    for (int q = 0; q < 16; ++q) acc[q] = 0.f;

    #pragma unroll 1
    for (int c = 0; c < 9; ++c) {                   // delta base -72 .. 56 step 16
        const int db = -72 + c * 16;
        float xb[31];
        #pragma unroll
        for (int j = 0; j < 31; ++j)
            xb[j] = vb[(ptrdiff_t)(db + j) * D_MODEL];
        #pragma unroll
        for (int dd = 0; dd < 16; ++dd) {
            const float w = wrow[db + dd + 87];     // LDS broadcast
            #pragma unroll
            for (int q = 0; q < 16; ++q)
                acc[q] = fmaf(w, xb[dd + q], acc[q]);
        }
    }

    float* ob = att + ((size_t)b * L_SEQ + q0) * D_MODEL + d;
    #pragma unroll
    for (int q = 0; q < 16; ++q)
        ob[(size_t)q * D_MODEL] = acc[q];
}

// ---------------------------------------------------------------------------
extern "C" void kernel_launch(void* const* d_in, const int* in_sizes, int n_in,
                              void* d_out, int out_size, void* d_ws, size_t ws_size,
                              hipStream_t stream)
{
    const float* values = (const float*)d_in[0];   // [B,L,D]
    const float* w_in   = (const float*)d_in[1];   // [D,D]
    const float* w_out  = (const float*)d_in[2];   // [D,D]
    float* out  = (float*)d_out;                   // [B,L,D]
    float* vpad = (float*)d_ws;                    // [B,LP,D]  (18.35 MB)
    float* att  = vpad + (size_t)B_SZ * LP * D_MODEL; // [B,L,D] (16.78 MB)

    zero_pads<<<dim3(4 * 96), dim3(256), 0, stream>>>(vpad);

    dim3 ggrid(1024 / 64, 4096 / 128);             // 16 x 32 = 512 blocks
    gemm_nt<1><<<ggrid, dim3(256), 0, stream>>>(values, w_in, vpad);

    dim3 cgrid(D_MODEL / 256, L_SEQ / 16, B_SZ);   // 4 x 128 x 2
    gauss_conv<<<cgrid, dim3(256), 0, stream>>>(vpad, att);

    gemm_nt<0><<<ggrid, dim3(256), 0, stream>>>(att, w_out, out);
}

// Round 2
// 175.181 us; speedup vs baseline: 1.8147x; 1.8147x over previous
//
#include <hip/hip_runtime.h>
#include <hip/hip_bf16.h>

// Problem constants (B=2, L=2048, D=1024, H=8, pd=128).
#define L_SEQ   2048
#define D_MODEL 1024
#define B_SZ    2
#define LP      (L_SEQ + 192)   // padded sequence length: 96 front + 96 back
#define PADF    96

typedef __attribute__((ext_vector_type(8))) short bf16x8;
typedef __attribute__((ext_vector_type(4))) float f32x4;

// async global->LDS, 16B per lane (global_load_lds_dwordx4)
__device__ __forceinline__ void gll16(const void* g, void* l) {
    __builtin_amdgcn_global_load_lds(
        (const __attribute__((address_space(1))) unsigned int*)(g),
        (__attribute__((address_space(3))) unsigned int*)(l),
        16, 0, 0);
}

__device__ __forceinline__ ushort bf16_hi(float x) {
    __hip_bfloat16 h = __float2bfloat16(x);
    return *reinterpret_cast<ushort*>(&h);
}
__device__ __forceinline__ float bf16_back(ushort u) {
    __hip_bfloat16 h = *reinterpret_cast<__hip_bfloat16*>(&u);
    return __bfloat162float(h);
}

// ---------------------------------------------------------------------------
// split_mat: fp32 -> bf16 hi plane + bf16 lo plane (lo = bf16(x - f32(hi))).
__global__ __launch_bounds__(256) void split_mat(const float* __restrict__ in,
                                                 ushort* __restrict__ hi,
                                                 ushort* __restrict__ lo)
{
    const size_t i = ((size_t)blockIdx.x * 256 + threadIdx.x) * 4;
    float4 v = *(const float4*)(in + i);
    float f[4] = {v.x, v.y, v.z, v.w};
    ushort hb[4], lb[4];
    #pragma unroll
    for (int j = 0; j < 4; ++j) {
        hb[j] = bf16_hi(f[j]);
        lb[j] = bf16_hi(f[j] - bf16_back(hb[j]));
    }
    ushort4 h = make_ushort4(hb[0], hb[1], hb[2], hb[3]);
    ushort4 l = make_ushort4(lb[0], lb[1], lb[2], lb[3]);
    *(ushort4*)(hi + i) = h;
    *(ushort4*)(lo + i) = l;
}

// ---------------------------------------------------------------------------
// zero_pads: zero the 4 pad regions of vpad [B][LP][D].
__global__ __launch_bounds__(256) void zero_pads(float* __restrict__ vpad)
{
    const int r  = blockIdx.x / 96;
    const int rr = blockIdx.x % 96;
    const int b  = r >> 1;
    const int row0 = (r & 1) ? (LP - 96) : 0;
    size_t off = ((size_t)b * LP + row0 + rr) * D_MODEL + threadIdx.x * 4;
    *(float4*)(vpad + off) = make_float4(0.f, 0.f, 0.f, 0.f);
}

// ---------------------------------------------------------------------------
// gemm_split: C[M,N] = (Ah+Al)*(Bh+Bl)^T via 3 bf16 MFMA products
//             (AhBh + AlBh + AhBl), fp32 accumulate. M=4096, N=K=1024.
// Tile 128(M) x 64(N), BK=32, 256 threads = 4 waves, each wave 64x32.
// LDS: Ah/Al[128][32] + Bh/Bl[64][32] bf16 = 24 KB, single-buffered (m97).
// DO_PAD=1 remaps output row m -> vpad row (b*LP + (m&2047) + PADF).
template<int DO_PAD>
__global__ __launch_bounds__(256) void gemm_split(const ushort* __restrict__ Ah,
                                                  const ushort* __restrict__ Al,
                                                  const ushort* __restrict__ Bh,
                                                  const ushort* __restrict__ Bl,
                                                  float* __restrict__ C)
{
    __shared__ __align__(16) ushort Ahs[128 * 32];
    __shared__ __align__(16) ushort Als[128 * 32];
    __shared__ __align__(16) ushort Bhs[64 * 32];
    __shared__ __align__(16) ushort Bls[64 * 32];

    const int tid = threadIdx.x;
    const int w   = tid >> 6;      // wave 0..3
    const int l   = tid & 63;      // lane

    // XCD-aware swizzle (512 blocks, 512%8==0 -> bijective):
    // XCD x gets swz in [x*64, x*64+64) = 4 contiguous m-panels -> L2 reuse.
    const int swz   = (blockIdx.x & 7) * 64 + (blockIdx.x >> 3);
    const int bm    = (swz >> 4) * 128;   // 32 m-tiles
    const int bn    = (swz & 15) * 64;    // 16 n-tiles

    // --- staging maps (global_load_lds: LDS dest = linear, 16B/lane) ---
    // A tiles (8192B): wave w, chunk i in {0,1}: LDS byte = w*2048+i*1024+l*16
    //   -> row = w*32 + i*16 + l/4, k-byte = (l&3)*16.
    const int arow = w * 32 + (l >> 2);
    const int akc  = (l & 3) * 8;                    // k offset in elements
    const ushort* gAh0 = Ah + (size_t)(bm + arow) * 1024 + akc;
    const ushort* gAh1 = gAh0 + (size_t)16 * 1024;
    const ushort* gAl0 = Al + (size_t)(bm + arow) * 1024 + akc;
    const ushort* gAl1 = gAl0 + (size_t)16 * 1024;
    ushort* lAh0 = Ahs + w * 1024 + l * 8;
    ushort* lAh1 = lAh0 + 512;
    ushort* lAl0 = Als + w * 1024 + l * 8;
    ushort* lAl1 = lAl0 + 512;
    // B tiles (4096B): LDS byte = tid*16 -> row = tid/4 = w*16 + l/4.
    const int brow = w * 16 + (l >> 2);
    const ushort* gBh = Bh + (size_t)(bn + brow) * 1024 + akc;
    const ushort* gBl = Bl + (size_t)(bn + brow) * 1024 + akc;
    ushort* lBh = Bhs + tid * 8;
    ushort* lBl = Bls + tid * 8;

    // --- per-wave output: wr=w>>1 -> m off 64; wc=w&1 -> n off 32 ---
    const int wr = w >> 1, wc = w & 1;
    const int fr = l & 15;        // row within fragment
    const int fq = l >> 4;        // k-chunk (0..3)

    f32x4 acc[4][2];
    #pragma unroll
    for (int mi = 0; mi < 4; ++mi)
        #pragma unroll
        for (int ni = 0; ni < 2; ++ni) acc[mi][ni] = (f32x4){0.f, 0.f, 0.f, 0.f};

    for (int kt = 0; kt < 1024; kt += 32) {
        gll16(gAh0 + kt, lAh0);
        gll16(gAh1 + kt, lAh1);
        gll16(gAl0 + kt, lAl0);
        gll16(gAl1 + kt, lAl1);
        gll16(gBh + kt, lBh);
        gll16(gBl + kt, lBl);
        __syncthreads();   // vmcnt(0) drain -> tiles ready

        bf16x8 ah[4], al[4];
        #pragma unroll
        for (int mi = 0; mi < 4; ++mi) {
            const int row = wr * 64 + mi * 16 + fr;
            ah[mi] = *(const bf16x8*)(Ahs + row * 32 + fq * 8);
            al[mi] = *(const bf16x8*)(Als + row * 32 + fq * 8);
        }
        #pragma unroll
        for (int ni = 0; ni < 2; ++ni) {
            const int row = wc * 32 + ni * 16 + fr;
            bf16x8 bh = *(const bf16x8*)(Bhs + row * 32 + fq * 8);
            bf16x8 bl = *(const bf16x8*)(Bls + row * 32 + fq * 8);
            #pragma unroll
            for (int mi = 0; mi < 4; ++mi)
                acc[mi][ni] = __builtin_amdgcn_mfma_f32_16x16x32_bf16(ah[mi], bh, acc[mi][ni], 0, 0, 0);
            #pragma unroll
            for (int mi = 0; mi < 4; ++mi)
                acc[mi][ni] = __builtin_amdgcn_mfma_f32_16x16x32_bf16(al[mi], bh, acc[mi][ni], 0, 0, 0);
            #pragma unroll
            for (int mi = 0; mi < 4; ++mi)
                acc[mi][ni] = __builtin_amdgcn_mfma_f32_16x16x32_bf16(ah[mi], bl, acc[mi][ni], 0, 0, 0);
        }
        __syncthreads();   // all waves done reading before next overwrite
    }

    // epilogue: C/D layout col=lane&15, row=(lane>>4)*4+reg  [m89/m91]
    #pragma unroll
    for (int mi = 0; mi < 4; ++mi) {
        #pragma unroll
        for (int ni = 0; ni < 2; ++ni) {
            const int col = bn + wc * 32 + ni * 16 + fr;
            #pragma unroll
            for (int j = 0; j < 4; ++j) {
                const int m = bm + wr * 64 + mi * 16 + fq * 4 + j;
                const size_t row = DO_PAD ? ((size_t)(m >> 11) * LP + (m & (L_SEQ - 1)) + PADF)
                                          : (size_t)m;
                C[row * 1024 + col] = acc[mi][ni][j];
            }
        }
    }
}

// ---------------------------------------------------------------------------
// gauss_conv_split: att[b,q,d] = sum_delta w[h(d)][delta] * vpad[b,q+delta,d],
// emitted directly as bf16 hi/lo planes for the second GEMM.
__global__ __launch_bounds__(256) void gauss_conv_split(const float* __restrict__ vpad,
                                                        ushort* __restrict__ Oh,
                                                        ushort* __restrict__ Ol)
{
    __shared__ float wt[8 * 160];   // head-major; index = h*160 + (delta + 87)
    const int tid = threadIdx.x;
    for (int i = tid; i < 8 * 160; i += 256) {
        const int h   = i / 160;
        const int dlt = (i % 160) - 87;
        const float sig = (float)(1 << (h & 3));   // std 1,2,4,8 ; offset = -std
        const float t = ((float)dlt + sig) / sig;
        wt[i] = (0.39894228040143267794f / sig) * expf(-0.5f * t * t);
    }
    __syncthreads();

    const int d  = blockIdx.x * 256 + tid;          // 0..1023
    const int q0 = blockIdx.y * 16;                 // 0..2032
    const int b  = blockIdx.z;
    const float* wrow = &wt[(d >> 7) * 160];        // wave-uniform head
    const float* vb = vpad + ((size_t)b * LP + PADF + q0) * D_MODEL + d;

    float acc[16];
    #pragma unroll
    for (int q = 0; q < 16; ++q) acc[q] = 0.f;

    #pragma unroll 1
    for (int c = 0; c < 9; ++c) {                   // delta base -72 .. 56 step 16
        const int db = -72 + c * 16;
        float xb[31];
        #pragma unroll
        for (int j = 0; j < 31; ++j)
            xb[j] = vb[(ptrdiff_t)(db + j) * D_MODEL];
        #pragma unroll
        for (int dd = 0; dd < 16; ++dd) {
            const float w = wrow[db + dd + 87];
            #pragma unroll
            for (int q = 0; q < 16; ++q)
                acc[q] = fmaf(w, xb[dd + q], acc[q]);
        }
    }

    ushort* oh = Oh + ((size_t)b * L_SEQ + q0) * D_MODEL + d;
    ushort* ol = Ol + ((size_t)b * L_SEQ + q0) * D_MODEL + d;
    #pragma unroll
    for (int q = 0; q < 16; ++q) {
        const ushort h = bf16_hi(acc[q]);
        oh[(size_t)q * D_MODEL] = h;
        ol[(size_t)q * D_MODEL] = bf16_hi(acc[q] - bf16_back(h));
    }
}

// ---------------------------------------------------------------------------
extern "C" void kernel_launch(void* const* d_in, const int* in_sizes, int n_in,
                              void* d_out, int out_size, void* d_ws, size_t ws_size,
                              hipStream_t stream)
{
    const float* values = (const float*)d_in[0];   // [B,L,D]
    const float* w_in   = (const float*)d_in[1];   // [D,D]
    const float* w_out  = (const float*)d_in[2];   // [D,D]
    float* out = (float*)d_out;                    // [B,L,D]

    // workspace layout (39.3 MB total)
    float*  vpad = (float*)d_ws;                                  // [B][LP][D] fp32
    ushort* Ph = (ushort*)(vpad + (size_t)B_SZ * LP * D_MODEL);   // [4096][1024] bf16 hi
    ushort* Pl = Ph + (size_t)4096 * 1024;                        // lo
    ushort* Wh = Pl + (size_t)4096 * 1024;                        // [1024][1024] bf16 hi
    ushort* Wl = Wh + (size_t)1024 * 1024;                        // lo

    // 1) split values + w_in into bf16 hi/lo planes
    split_mat<<<dim3(4096), dim3(256), 0, stream>>>(values, Ph, Pl);
    split_mat<<<dim3(1024), dim3(256), 0, stream>>>(w_in, Wh, Wl);
    zero_pads<<<dim3(4 * 96), dim3(256), 0, stream>>>(vpad);

    // 2) v = values @ w_in^T  (into padded fp32 buffer)
    gemm_split<1><<<dim3(512), dim3(256), 0, stream>>>(Ph, Pl, Wh, Wl, vpad);

    // 3) Gaussian conv -> att, emitted as bf16 hi/lo planes (reuses Ph/Pl)
    dim3 cgrid(D_MODEL / 256, L_SEQ / 16, B_SZ);
    gauss_conv_split<<<cgrid, dim3(256), 0, stream>>>(vpad, Ph, Pl);

    // 4) split w_out (reuses Wh/Wl), then out = att @ w_out^T
    split_mat<<<dim3(1024), dim3(256), 0, stream>>>(w_out, Wh, Wl);
    gemm_split<0><<<dim3(512), dim3(256), 0, stream>>>(Ph, Pl, Wh, Wl, out);
}

// Round 3
// 162.359 us; speedup vs baseline: 1.9580x; 1.0790x over previous
//
#include <hip/hip_runtime.h>
#include <hip/hip_bf16.h>

// Problem constants (B=2, L=2048, D=1024, H=8, pd=128).
#define L_SEQ   2048
#define D_MODEL 1024
#define B_SZ    2
#define LP      (L_SEQ + 192)   // padded sequence length: 96 front + 96 back
#define PADF    96

typedef __attribute__((ext_vector_type(8))) short bf16x8;
typedef __attribute__((ext_vector_type(4))) float f32x4;

// async global->LDS, 16B per lane (global_load_lds_dwordx4)
__device__ __forceinline__ void gll16(const void* g, void* l) {
    __builtin_amdgcn_global_load_lds(
        (const __attribute__((address_space(1))) unsigned int*)(g),
        (__attribute__((address_space(3))) unsigned int*)(l),
        16, 0, 0);
}

__device__ __forceinline__ ushort bf16_hi(float x) {
    __hip_bfloat16 h = __float2bfloat16(x);
    return *reinterpret_cast<ushort*>(&h);
}
__device__ __forceinline__ float bf16_back(ushort u) {
    __hip_bfloat16 h = *reinterpret_cast<__hip_bfloat16*>(&u);
    return __bfloat162float(h);
}

// ---------------------------------------------------------------------------
// split_mat: fp32 -> bf16 hi plane + bf16 lo plane (lo = bf16(x - f32(hi))).
__global__ __launch_bounds__(256) void split_mat(const float* __restrict__ in,
                                                 ushort* __restrict__ hi,
                                                 ushort* __restrict__ lo)
{
    const size_t i = ((size_t)blockIdx.x * 256 + threadIdx.x) * 4;
    float4 v = *(const float4*)(in + i);
    float f[4] = {v.x, v.y, v.z, v.w};
    ushort hb[4], lb[4];
    #pragma unroll
    for (int j = 0; j < 4; ++j) {
        hb[j] = bf16_hi(f[j]);
        lb[j] = bf16_hi(f[j] - bf16_back(hb[j]));
    }
    *(ushort4*)(hi + i) = make_ushort4(hb[0], hb[1], hb[2], hb[3]);
    *(ushort4*)(lo + i) = make_ushort4(lb[0], lb[1], lb[2], lb[3]);
}

// ---------------------------------------------------------------------------
// zero_pads: zero the 4 pad regions of vpad [B][LP][D].
__global__ __launch_bounds__(256) void zero_pads(float* __restrict__ vpad)
{
    const int r  = blockIdx.x / 96;
    const int rr = blockIdx.x % 96;
    const int b  = r >> 1;
    const int row0 = (r & 1) ? (LP - 96) : 0;
    size_t off = ((size_t)b * LP + row0 + rr) * D_MODEL + threadIdx.x * 4;
    *(float4*)(vpad + off) = make_float4(0.f, 0.f, 0.f, 0.f);
}

// ---------------------------------------------------------------------------
// gemm_split: C[M,N] = (Ah+Al)*(Bh+Bl)^T via 3 bf16 MFMA products, fp32 acc.
// M=4096, N=K=1024. Tile 128x128, BK=32, 512 threads = 8 waves (2m x 4n),
// each wave 64x32. LDS double-buffered 2 x 4 planes x 8KB = 64KB.
// Bank-conflict fix: k-chunk XOR swizzle, applied on the global SOURCE
// address (global_load_lds dest must stay linear) and on the ds_read side
// with the same involution chunk' = chunk ^ ((row>>1)&3).
// 2-phase pipeline: STAGE(t+1) issued before compute(t); __syncthreads'
// vmcnt(0)+barrier at loop end covers both hazards.
// DO_PAD=1 remaps output row m -> vpad row (b*LP + (m&2047) + PADF).
template<int DO_PAD>
__global__ __launch_bounds__(512) void gemm_split(const ushort* __restrict__ Ah,
                                                  const ushort* __restrict__ Al,
                                                  const ushort* __restrict__ Bh,
                                                  const ushort* __restrict__ Bl,
                                                  float* __restrict__ C)
{
    // [buf][plane][128 rows * 32 k]  plane: 0=Ah 1=Al 2=Bh 3=Bl
    __shared__ __align__(16) ushort lds[2][4][128 * 32];

    const int tid = threadIdx.x;
    const int w   = tid >> 6;
    const int l   = tid & 63;

    // XCD slab swizzle: 256 blocks, xcd = blk&7 owns a 4m x 8n slab.
    const int xcd = blockIdx.x & 7;
    const int idx = blockIdx.x >> 3;                 // 0..31
    const int bm  = (xcd * 4 + (idx >> 3)) * 128;    // 32 m-tiles
    const int bn  = (idx & 7) * 128;                 // 8 n-tiles

    // --- staging: 512 threads x 16B = 8KB = one full plane per issue ---
    const int srow   = tid >> 2;                          // 0..127
    const int schunk = (tid & 3) ^ ((tid >> 3) & 3);      // pre-swizzled source chunk
    const ushort* gAh = Ah + (size_t)(bm + srow) * 1024 + schunk * 8;
    const ushort* gAl = Al + (size_t)(bm + srow) * 1024 + schunk * 8;
    const ushort* gBh = Bh + (size_t)(bn + srow) * 1024 + schunk * 8;
    const ushort* gBl = Bl + (size_t)(bn + srow) * 1024 + schunk * 8;
    const int ldst = tid * 8;                             // linear LDS dest (ushort)

    // --- fragment read params ---
    const int fr  = l & 15;                // row within 16x16 fragment
    const int fq  = l >> 4;                // k-chunk 0..3
    const int swz = (fr >> 1) & 3;         // (row>>1)&3, row-base multiple of 16
    const int rdo = (fq ^ swz) << 3;       // element offset of swizzled chunk
    const int wr  = w >> 2;                // 0..1  -> m offset wr*64
    const int wc  = w & 3;                 // 0..3  -> n offset wc*32

    f32x4 acc[4][2];
    #pragma unroll
    for (int mi = 0; mi < 4; ++mi)
        #pragma unroll
        for (int ni = 0; ni < 2; ++ni) acc[mi][ni] = (f32x4){0.f, 0.f, 0.f, 0.f};

    #define STAGE(buf, kt)                                        \
        do {                                                      \
            const size_t ko_ = (size_t)(kt) * 32;                 \
            gll16(gAh + ko_, &lds[(buf)][0][ldst]);               \
            gll16(gAl + ko_, &lds[(buf)][1][ldst]);               \
            gll16(gBh + ko_, &lds[(buf)][2][ldst]);               \
            gll16(gBl + ko_, &lds[(buf)][3][ldst]);               \
        } while (0)

    STAGE(0, 0);
    __syncthreads();

    for (int kt = 0; kt < 32; ++kt) {
        const int cur = kt & 1;
        if (kt + 1 < 32) STAGE(cur ^ 1, kt + 1);   // prefetch overlaps MFMA below

        bf16x8 ah[4], al[4];
        #pragma unroll
        for (int mi = 0; mi < 4; ++mi) {
            const int row = wr * 64 + mi * 16 + fr;
            ah[mi] = *(const bf16x8*)&lds[cur][0][row * 32 + rdo];
            al[mi] = *(const bf16x8*)&lds[cur][1][row * 32 + rdo];
        }
        #pragma unroll
        for (int ni = 0; ni < 2; ++ni) {
            const int row = wc * 32 + ni * 16 + fr;
            bf16x8 bh = *(const bf16x8*)&lds[cur][2][row * 32 + rdo];
            bf16x8 bl = *(const bf16x8*)&lds[cur][3][row * 32 + rdo];
            #pragma unroll
            for (int mi = 0; mi < 4; ++mi)
                acc[mi][ni] = __builtin_amdgcn_mfma_f32_16x16x32_bf16(ah[mi], bh, acc[mi][ni], 0, 0, 0);
            #pragma unroll
            for (int mi = 0; mi < 4; ++mi)
                acc[mi][ni] = __builtin_amdgcn_mfma_f32_16x16x32_bf16(al[mi], bh, acc[mi][ni], 0, 0, 0);
            #pragma unroll
            for (int mi = 0; mi < 4; ++mi)
                acc[mi][ni] = __builtin_amdgcn_mfma_f32_16x16x32_bf16(ah[mi], bl, acc[mi][ni], 0, 0, 0);
        }
        __syncthreads();   // drains prefetch vmcnt + guards buffer reuse
    }
    #undef STAGE

    // epilogue: C/D layout col=lane&15, row=(lane>>4)*4+reg  [m89/m91]
    #pragma unroll
    for (int mi = 0; mi < 4; ++mi) {
        #pragma unroll
        for (int ni = 0; ni < 2; ++ni) {
            const int col = bn + wc * 32 + ni * 16 + fr;
            #pragma unroll
            for (int j = 0; j < 4; ++j) {
                const int m = bm + wr * 64 + mi * 16 + fq * 4 + j;
                const size_t row = DO_PAD ? ((size_t)(m >> 11) * LP + (m & (L_SEQ - 1)) + PADF)
                                          : (size_t)m;
                C[row * 1024 + col] = acc[mi][ni][j];
            }
        }
    }
}

// ---------------------------------------------------------------------------
// gauss_conv_split: att[b,q,d] = sum_{delta=-71..56} w[h][delta]*vpad[b,q+delta,d]
// (delta=-72 term <= 5e-16, dropped). Block = 64 d-cols x 128 q-rows; stages
// 256 rows x 64 floats (64KB) in LDS once; each thread owns one d-column and
// 32 q-accumulators, sliding a 47-register window per 16-delta chunk.
// Emits bf16 hi/lo planes directly.
__global__ __launch_bounds__(256) void gauss_conv_split(const float* __restrict__ vpad,
                                                        ushort* __restrict__ Oh,
                                                        ushort* __restrict__ Ol)
{
    __shared__ __align__(16) float xs[256 * 64];   // [row][d] 64KB
    __shared__ float wt[128];                      // delta = j - 71

    const int tid = threadIdx.x;
    const int d0  = blockIdx.x * 64;
    const int q0  = blockIdx.y * 128;
    const int b   = blockIdx.z;
    const int h   = blockIdx.x >> 1;               // 64-wide d block => single head

    if (tid < 128) {
        const float sig = (float)(1 << (h & 3));   // std 1,2,4,8 ; offset = -std
        const float t = ((float)(tid - 71) + sig) / sig;
        wt[tid] = (0.39894228040143267794f / sig) * expf(-0.5f * t * t);
    }

    // stage rows [q0-71, q0+184] x [d0, d0+64)
    const float* src = vpad + ((size_t)b * LP + (PADF - 71) + q0) * 1024 + d0;
    #pragma unroll
    for (int p = 0; p < 16; ++p) {
        const int f   = p * 256 + tid;             // float4 index
        const int row = f >> 4;
        const int c4  = (f & 15) * 4;
        gll16(src + (size_t)row * 1024 + c4, &xs[f * 4]);
    }
    __syncthreads();

    const int d     = tid & 63;
    const int qbase = (tid >> 6) * 32;

    float acc[32];
    #pragma unroll
    for (int qq = 0; qq < 32; ++qq) acc[qq] = 0.f;

    #pragma unroll 1
    for (int c = 0; c < 8; ++c) {
        float xw[47];
        const float* xp = &xs[(qbase + c * 16) * 64 + d];
        #pragma unroll
        for (int j = 0; j < 47; ++j) xw[j] = xp[j * 64];
        #pragma unroll
        for (int dd = 0; dd < 16; ++dd) {
            const float wv = wt[c * 16 + dd];      // block-uniform broadcast
            #pragma unroll
            for (int qq = 0; qq < 32; ++qq)
                acc[qq] = fmaf(wv, xw[dd + qq], acc[qq]);
        }
    }

    ushort* oh = Oh + ((size_t)b * L_SEQ + q0 + qbase) * 1024 + d0 + d;
    ushort* ol = Ol + ((size_t)b * L_SEQ + q0 + qbase) * 1024 + d0 + d;
    #pragma unroll
    for (int qq = 0; qq < 32; ++qq) {
        const ushort hv = bf16_hi(acc[qq]);
        oh[(size_t)qq * 1024] = hv;
        ol[(size_t)qq * 1024] = bf16_hi(acc[qq] - bf16_back(hv));
    }
}

// ---------------------------------------------------------------------------
extern "C" void kernel_launch(void* const* d_in, const int* in_sizes, int n_in,
                              void* d_out, int out_size, void* d_ws, size_t ws_size,
                              hipStream_t stream)
{
    const float* values = (const float*)d_in[0];   // [B,L,D]
    const float* w_in   = (const float*)d_in[1];   // [D,D]
    const float* w_out  = (const float*)d_in[2];   // [D,D]
    float* out = (float*)d_out;                    // [B,L,D]

    // workspace layout (39.3 MB total)
    float*  vpad = (float*)d_ws;                                  // [B][LP][D] fp32
    ushort* Ph = (ushort*)(vpad + (size_t)B_SZ * LP * D_MODEL);   // [4096][1024] bf16 hi
    ushort* Pl = Ph + (size_t)4096 * 1024;                        // lo
    ushort* Wh = Pl + (size_t)4096 * 1024;                        // [1024][1024] bf16 hi
    ushort* Wl = Wh + (size_t)1024 * 1024;                        // lo

    // 1) split values + w_in into bf16 hi/lo planes
    split_mat<<<dim3(4096), dim3(256), 0, stream>>>(values, Ph, Pl);
    split_mat<<<dim3(1024), dim3(256), 0, stream>>>(w_in, Wh, Wl);
    zero_pads<<<dim3(4 * 96), dim3(256), 0, stream>>>(vpad);

    // 2) v = values @ w_in^T  (into padded fp32 buffer)
    gemm_split<1><<<dim3(256), dim3(512), 0, stream>>>(Ph, Pl, Wh, Wl, vpad);

    // 3) Gaussian conv -> att, emitted as bf16 hi/lo planes (reuses Ph/Pl)
    dim3 cgrid(D_MODEL / 64, L_SEQ / 128, B_SZ);   // 16 x 16 x 2 = 512 blocks
    gauss_conv_split<<<cgrid, dim3(256), 0, stream>>>(vpad, Ph, Pl);

    // 4) split w_out (reuses Wh/Wl), then out = att @ w_out^T
    split_mat<<<dim3(1024), dim3(256), 0, stream>>>(w_out, Wh, Wl);
    gemm_split<0><<<dim3(256), dim3(512), 0, stream>>>(Ph, Pl, Wh, Wl, out);
}

// Round 5
// 153.175 us; speedup vs baseline: 2.0754x; 1.0600x over previous
//
#include <hip/hip_runtime.h>
#include <hip/hip_bf16.h>

// Problem constants (B=2, L=2048, D=1024, H=8, pd=128).
#define L_SEQ   2048
#define D_MODEL 1024
#define B_SZ    2
#define LP      (L_SEQ + 192)   // padded sequence length: 96 front + 96 back
#define PADF    96

typedef __attribute__((ext_vector_type(8))) short bf16x8;
typedef __attribute__((ext_vector_type(4))) float f32x4;

// async global->LDS, 16B per lane (global_load_lds_dwordx4)
__device__ __forceinline__ void gll16(const void* g, void* l) {
    __builtin_amdgcn_global_load_lds(
        (const __attribute__((address_space(1))) unsigned int*)(g),
        (__attribute__((address_space(3))) unsigned int*)(l),
        16, 0, 0);
}

__device__ __forceinline__ ushort bf16_hi(float x) {
    __hip_bfloat16 h = __float2bfloat16(x);
    return *reinterpret_cast<ushort*>(&h);
}
__device__ __forceinline__ float bf16_back(ushort u) {
    __hip_bfloat16 h = *reinterpret_cast<__hip_bfloat16*>(&u);
    return __bfloat162float(h);
}

// ---------------------------------------------------------------------------
// split_mat: fp32 -> bf16 hi plane + bf16 lo plane (lo = bf16(x - f32(hi))).
__global__ __launch_bounds__(256) void split_mat(const float* __restrict__ in,
                                                 ushort* __restrict__ hi,
                                                 ushort* __restrict__ lo)
{
    const size_t i = ((size_t)blockIdx.x * 256 + threadIdx.x) * 4;
    float4 v = *(const float4*)(in + i);
    float f[4] = {v.x, v.y, v.z, v.w};
    ushort hb[4], lb[4];
    #pragma unroll
    for (int j = 0; j < 4; ++j) {
        hb[j] = bf16_hi(f[j]);
        lb[j] = bf16_hi(f[j] - bf16_back(hb[j]));
    }
    *(ushort4*)(hi + i) = make_ushort4(hb[0], hb[1], hb[2], hb[3]);
    *(ushort4*)(lo + i) = make_ushort4(lb[0], lb[1], lb[2], lb[3]);
}

// split_w: both weight matrices in one launch (blocks 0..1023 -> w_in,
// 1024..2047 -> w_out).
__global__ __launch_bounds__(256) void split_w(const float* __restrict__ w_in,
                                               const float* __restrict__ w_out,
                                               ushort* __restrict__ Wh,
                                               ushort* __restrict__ Wl,
                                               ushort* __restrict__ W2h,
                                               ushort* __restrict__ W2l)
{
    const int sel = blockIdx.x >> 10;
    const float* src = sel ? w_out : w_in;
    ushort* oh = sel ? W2h : Wh;
    ushort* ol = sel ? W2l : Wl;
    const size_t i = ((size_t)(blockIdx.x & 1023) * 256 + threadIdx.x) * 4;
    float4 v = *(const float4*)(src + i);
    float f[4] = {v.x, v.y, v.z, v.w};
    ushort hb[4], lb[4];
    #pragma unroll
    for (int j = 0; j < 4; ++j) {
        hb[j] = bf16_hi(f[j]);
        lb[j] = bf16_hi(f[j] - bf16_back(hb[j]));
    }
    *(ushort4*)(oh + i) = make_ushort4(hb[0], hb[1], hb[2], hb[3]);
    *(ushort4*)(ol + i) = make_ushort4(lb[0], lb[1], lb[2], lb[3]);
}

// ---------------------------------------------------------------------------
// zero_pads: zero the 4 pad regions of vpad [B][LP][D].
__global__ __launch_bounds__(256) void zero_pads(float* __restrict__ vpad)
{
    const int r  = blockIdx.x / 96;
    const int rr = blockIdx.x % 96;
    const int b  = r >> 1;
    const int row0 = (r & 1) ? (LP - 96) : 0;
    size_t off = ((size_t)b * LP + row0 + rr) * D_MODEL + threadIdx.x * 4;
    *(float4*)(vpad + off) = make_float4(0.f, 0.f, 0.f, 0.f);
}

// ---------------------------------------------------------------------------
// gemm_split: C[M,N] = (Ah+Al)*(Bh+Bl)^T via 3 bf16 MFMA products, fp32 acc.
// M=4096, N=K=1024. Tile 128x128, BK=32, 512 threads = 8 waves (2m x 4n).
// T4 counted-vmcnt pipeline: 4 LDS buffers (4 x 32KB = 128KB), tile kt+3
// staged at iteration kt, `s_waitcnt vmcnt(8); s_barrier` before reading
// buf[kt&3] (8 = 2 younger tiles x 4 loads in flight). No vmcnt(0) drain in
// the main loop. Bank-conflict fix: k-chunk XOR swizzle on global SOURCE
// (global_load_lds dest linear) + same involution on ds_read.
// DO_PAD=1 remaps output row m -> vpad row (b*LP + (m&2047) + PADF).
template<int DO_PAD>
__global__ __launch_bounds__(512) void gemm_split(const ushort* __restrict__ Ah,
                                                  const ushort* __restrict__ Al,
                                                  const ushort* __restrict__ Bh,
                                                  const ushort* __restrict__ Bl,
                                                  float* __restrict__ C)
{
    // [buf][plane][128 rows * 32 k]  plane: 0=Ah 1=Al 2=Bh 3=Bl
    __shared__ __align__(16) ushort lds[4][4][128 * 32];

    const int tid = threadIdx.x;
    const int w   = tid >> 6;
    const int l   = tid & 63;

    // XCD slab swizzle: 256 blocks, xcd = blk&7 owns a 4m x 8n slab.
    const int xcd = blockIdx.x & 7;
    const int idx = blockIdx.x >> 3;                 // 0..31
    const int bm  = (xcd * 4 + (idx >> 3)) * 128;    // 32 m-tiles
    const int bn  = (idx & 7) * 128;                 // 8 n-tiles

    // --- staging: 512 threads x 16B = 8KB = one full plane per issue ---
    const int srow   = tid >> 2;                          // 0..127
    const int schunk = (tid & 3) ^ ((tid >> 3) & 3);      // pre-swizzled source chunk
    const ushort* gAh = Ah + (size_t)(bm + srow) * 1024 + schunk * 8;
    const ushort* gAl = Al + (size_t)(bm + srow) * 1024 + schunk * 8;
    const ushort* gBh = Bh + (size_t)(bn + srow) * 1024 + schunk * 8;
    const ushort* gBl = Bl + (size_t)(bn + srow) * 1024 + schunk * 8;
    const int ldst = tid * 8;                             // linear LDS dest (ushort)

    // --- fragment read params ---
    const int fr  = l & 15;                // row within 16x16 fragment
    const int fq  = l >> 4;                // k-chunk 0..3
    const int swz = (fr >> 1) & 3;         // (row>>1)&3, row-base multiple of 16
    const int rdo = (fq ^ swz) << 3;       // element offset of swizzled chunk
    const int wr  = w >> 2;                // 0..1  -> m offset wr*64
    const int wc  = w & 3;                 // 0..3  -> n offset wc*32

    f32x4 acc[4][2];
    #pragma unroll
    for (int mi = 0; mi < 4; ++mi)
        #pragma unroll
        for (int ni = 0; ni < 2; ++ni) acc[mi][ni] = (f32x4){0.f, 0.f, 0.f, 0.f};

    #define STAGE(buf, kt)                                        \
        do {                                                      \
            const size_t ko_ = (size_t)(kt) * 32;                 \
            gll16(gAh + ko_, &lds[(buf)][0][ldst]);               \
            gll16(gAl + ko_, &lds[(buf)][1][ldst]);               \
            gll16(gBh + ko_, &lds[(buf)][2][ldst]);               \
            gll16(gBl + ko_, &lds[(buf)][3][ldst]);               \
        } while (0)

    // WAITBAR(N): my tile-(kt) loads retired (N younger stay in flight),
    // then barrier -> ALL waves' tile-(kt) loads are in LDS.
    #define WAITBAR(N) asm volatile("s_waitcnt vmcnt(" #N ")\n\ts_barrier" ::: "memory")

    #define COMPUTE(cur)                                                                   \
        do {                                                                               \
            bf16x8 ah[4], al[4];                                                           \
            _Pragma("unroll")                                                              \
            for (int mi = 0; mi < 4; ++mi) {                                               \
                const int row = wr * 64 + mi * 16 + fr;                                    \
                ah[mi] = *(const bf16x8*)&lds[(cur)][0][row * 32 + rdo];                   \
                al[mi] = *(const bf16x8*)&lds[(cur)][1][row * 32 + rdo];                   \
            }                                                                              \
            _Pragma("unroll")                                                              \
            for (int ni = 0; ni < 2; ++ni) {                                               \
                const int row = wc * 32 + ni * 16 + fr;                                    \
                bf16x8 bh = *(const bf16x8*)&lds[(cur)][2][row * 32 + rdo];                \
                bf16x8 bl = *(const bf16x8*)&lds[(cur)][3][row * 32 + rdo];                \
                _Pragma("unroll")                                                          \
                for (int mi = 0; mi < 4; ++mi)                                             \
                    acc[mi][ni] = __builtin_amdgcn_mfma_f32_16x16x32_bf16(ah[mi], bh, acc[mi][ni], 0, 0, 0); \
                _Pragma("unroll")                                                          \
                for (int mi = 0; mi < 4; ++mi)                                             \
                    acc[mi][ni] = __builtin_amdgcn_mfma_f32_16x16x32_bf16(al[mi], bh, acc[mi][ni], 0, 0, 0); \
                _Pragma("unroll")                                                          \
                for (int mi = 0; mi < 4; ++mi)                                             \
                    acc[mi][ni] = __builtin_amdgcn_mfma_f32_16x16x32_bf16(ah[mi], bl, acc[mi][ni], 0, 0, 0); \
            }                                                                              \
        } while (0)

    STAGE(0, 0);
    STAGE(1, 1);
    STAGE(2, 2);

    for (int kt = 0; kt < 29; ++kt) {
        WAITBAR(8);
        STAGE((kt + 3) & 3, kt + 3);
        COMPUTE(kt & 3);
    }
    WAITBAR(8); COMPUTE(1);   // kt=29
    WAITBAR(4); COMPUTE(2);   // kt=30
    WAITBAR(0); COMPUTE(3);   // kt=31

    #undef STAGE
    #undef WAITBAR
    #undef COMPUTE

    // epilogue: C/D layout col=lane&15, row=(lane>>4)*4+reg  [m89/m91]
    #pragma unroll
    for (int mi = 0; mi < 4; ++mi) {
        #pragma unroll
        for (int ni = 0; ni < 2; ++ni) {
            const int col = bn + wc * 32 + ni * 16 + fr;
            #pragma unroll
            for (int j = 0; j < 4; ++j) {
                const int m = bm + wr * 64 + mi * 16 + fq * 4 + j;
                const size_t row = DO_PAD ? ((size_t)(m >> 11) * LP + (m & (L_SEQ - 1)) + PADF)
                                          : (size_t)m;
                C[row * 1024 + col] = acc[mi][ni][j];
            }
        }
    }
}

// ---------------------------------------------------------------------------
// gauss_conv_split: att[b,q,d] = sum_{delta=-71..56} w[h][delta]*vpad[b,q+delta,d]
// (delta=-72 term <= 5e-16, dropped). Block = 64 d-cols x 128 q-rows; stages
// 256 rows x 64 floats (64KB) in LDS once; each thread owns one d-column and
// 32 q-accumulators, sliding a 47-register window per 16-delta chunk.
// Emits bf16 hi/lo planes directly.
__global__ __launch_bounds__(256) void gauss_conv_split(const float* __restrict__ vpad,
                                                        ushort* __restrict__ Oh,
                                                        ushort* __restrict__ Ol)
{
    __shared__ __align__(16) float xs[256 * 64];   // [row][d] 64KB
    __shared__ float wt[128];                      // delta = j - 71

    const int tid = threadIdx.x;
    const int d0  = blockIdx.x * 64;
    const int q0  = blockIdx.y * 128;
    const int b   = blockIdx.z;
    const int h   = blockIdx.x >> 1;               // 64-wide d block => single head

    if (tid < 128) {
        const float sig = (float)(1 << (h & 3));   // std 1,2,4,8 ; offset = -std
        const float t = ((float)(tid - 71) + sig) / sig;
        wt[tid] = (0.39894228040143267794f / sig) * expf(-0.5f * t * t);
    }

    // stage rows [q0-71, q0+184] x [d0, d0+64)
    const float* src = vpad + ((size_t)b * LP + (PADF - 71) + q0) * 1024 + d0;
    #pragma unroll
    for (int p = 0; p < 16; ++p) {
        const int f   = p * 256 + tid;             // float4 index
        const int row = f >> 4;
        const int c4  = (f & 15) * 4;
        gll16(src + (size_t)row * 1024 + c4, &xs[f * 4]);
    }
    __syncthreads();

    const int d     = tid & 63;
    const int qbase = (tid >> 6) * 32;

    float acc[32];
    #pragma unroll
    for (int qq = 0; qq < 32; ++qq) acc[qq] = 0.f;

    #pragma unroll 1
    for (int c = 0; c < 8; ++c) {
        float xw[47];
        const float* xp = &xs[(qbase + c * 16) * 64 + d];
        #pragma unroll
        for (int j = 0; j < 47; ++j) xw[j] = xp[j * 64];
        #pragma unroll
        for (int dd = 0; dd < 16; ++dd) {
            const float wv = wt[c * 16 + dd];      // block-uniform broadcast
            #pragma unroll
            for (int qq = 0; qq < 32; ++qq)
                acc[qq] = fmaf(wv, xw[dd + qq], acc[qq]);
        }
    }

    ushort* oh = Oh + ((size_t)b * L_SEQ + q0 + qbase) * 1024 + d0 + d;
    ushort* ol = Ol + ((size_t)b * L_SEQ + q0 + qbase) * 1024 + d0 + d;
    #pragma unroll
    for (int qq = 0; qq < 32; ++qq) {
        const ushort hv = bf16_hi(acc[qq]);
        oh[(size_t)qq * 1024] = hv;
        ol[(size_t)qq * 1024] = bf16_hi(acc[qq] - bf16_back(hv));
    }
}

// ---------------------------------------------------------------------------
extern "C" void kernel_launch(void* const* d_in, const int* in_sizes, int n_in,
                              void* d_out, int out_size, void* d_ws, size_t ws_size,
                              hipStream_t stream)
{
    const float* values = (const float*)d_in[0];   // [B,L,D]
    const float* w_in   = (const float*)d_in[1];   // [D,D]
    const float* w_out  = (const float*)d_in[2];   // [D,D]
    float* out = (float*)d_out;                    // [B,L,D]

    // workspace layout (43.5 MB total)
    float*  vpad = (float*)d_ws;                                  // [B][LP][D] fp32
    ushort* Ph  = (ushort*)(vpad + (size_t)B_SZ * LP * D_MODEL);  // [4096][1024] bf16 hi
    ushort* Pl  = Ph  + (size_t)4096 * 1024;                      // lo
    ushort* Wh  = Pl  + (size_t)4096 * 1024;                      // w_in hi
    ushort* Wl  = Wh  + (size_t)1024 * 1024;                      // w_in lo
    ushort* W2h = Wl  + (size_t)1024 * 1024;                      // w_out hi
    ushort* W2l = W2h + (size_t)1024 * 1024;                      // w_out lo

    // 1) split values + both weights into bf16 hi/lo planes
    split_mat<<<dim3(4096), dim3(256), 0, stream>>>(values, Ph, Pl);
    split_w<<<dim3(2048), dim3(256), 0, stream>>>(w_in, w_out, Wh, Wl, W2h, W2l);
    zero_pads<<<dim3(4 * 96), dim3(256), 0, stream>>>(vpad);

    // 2) v = values @ w_in^T  (into padded fp32 buffer)
    gemm_split<1><<<dim3(256), dim3(512), 0, stream>>>(Ph, Pl, Wh, Wl, vpad);

    // 3) Gaussian conv -> att, emitted as bf16 hi/lo planes (reuses Ph/Pl)
    dim3 cgrid(D_MODEL / 64, L_SEQ / 128, B_SZ);   // 16 x 16 x 2 = 512 blocks
    gauss_conv_split<<<cgrid, dim3(256), 0, stream>>>(vpad, Ph, Pl);

    // 4) out = att @ w_out^T
    gemm_split<0><<<dim3(256), dim3(512), 0, stream>>>(Ph, Pl, W2h, W2l, out);
}

// Round 6
// 151.234 us; speedup vs baseline: 2.1021x; 1.0128x over previous
//
#include <hip/hip_runtime.h>
#include <hip/hip_bf16.h>

// Problem constants (B=2, L=2048, D=1024, H=8, pd=128).
#define L_SEQ   2048
#define D_MODEL 1024
#define B_SZ    2
#define LP      (L_SEQ + 192)   // padded sequence length: 96 front + 96 back
#define PADF    96

typedef __attribute__((ext_vector_type(8))) short bf16x8;
typedef __attribute__((ext_vector_type(4))) float f32x4;

// async global->LDS, 16B per lane (global_load_lds_dwordx4)
__device__ __forceinline__ void gll16(const void* g, void* l) {
    __builtin_amdgcn_global_load_lds(
        (const __attribute__((address_space(1))) unsigned int*)(g),
        (__attribute__((address_space(3))) unsigned int*)(l),
        16, 0, 0);
}

__device__ __forceinline__ ushort bf16_hi(float x) {
    __hip_bfloat16 h = __float2bfloat16(x);
    return *reinterpret_cast<ushort*>(&h);
}
__device__ __forceinline__ float bf16_back(ushort u) {
    __hip_bfloat16 h = *reinterpret_cast<__hip_bfloat16*>(&u);
    return __bfloat162float(h);
}

// ---------------------------------------------------------------------------
// prep: one launch does (a) zero vpad pad rows [384 blocks], (b) split values
// [4096 blocks], (c) split w_in [1024], (d) split w_out [1024]. Whole blocks
// take one branch -> no divergence. Replaces 3 kernels (fewer graph gaps).
__global__ __launch_bounds__(256) void prep(const float* __restrict__ values,
                                            const float* __restrict__ w_in,
                                            const float* __restrict__ w_out,
                                            ushort* __restrict__ Ph, ushort* __restrict__ Pl,
                                            ushort* __restrict__ Wh, ushort* __restrict__ Wl,
                                            ushort* __restrict__ W2h, ushort* __restrict__ W2l,
                                            float* __restrict__ vpad)
{
    int blk = blockIdx.x;
    if (blk < 384) {                               // zero the 4 pad regions
        const int r  = blk / 96;
        const int rr = blk % 96;
        const int b  = r >> 1;
        const int row0 = (r & 1) ? (LP - 96) : 0;
        size_t off = ((size_t)b * LP + row0 + rr) * D_MODEL + threadIdx.x * 4;
        *(float4*)(vpad + off) = make_float4(0.f, 0.f, 0.f, 0.f);
        return;
    }
    blk -= 384;
    const float* src;
    ushort *oh, *ol;
    if (blk < 4096)      { src = values; oh = Ph;  ol = Pl;  }
    else if (blk < 5120) { src = w_in;   oh = Wh;  ol = Wl;  blk -= 4096; }
    else                 { src = w_out;  oh = W2h; ol = W2l; blk -= 5120; }

    const size_t i = ((size_t)blk * 256 + threadIdx.x) * 4;
    float4 v = *(const float4*)(src + i);
    float f[4] = {v.x, v.y, v.z, v.w};
    ushort hb[4], lb[4];
    #pragma unroll
    for (int j = 0; j < 4; ++j) {
        hb[j] = bf16_hi(f[j]);
        lb[j] = bf16_hi(f[j] - bf16_back(hb[j]));
    }
    *(ushort4*)(oh + i) = make_ushort4(hb[0], hb[1], hb[2], hb[3]);
    *(ushort4*)(ol + i) = make_ushort4(lb[0], lb[1], lb[2], lb[3]);
}

// ---------------------------------------------------------------------------
// gemm_split: C[M,N] = (Ah+Al)*(Bh+Bl)^T via 3 bf16 MFMA products, fp32 acc.
// M=4096, N=K=1024. Tile 128x128, BK=32, 512 threads = 8 waves (2m x 4n).
// T4 counted-vmcnt pipeline: 4 LDS buffers (4 x 32KB = 128KB), tile kt+3
// staged at iteration kt, `s_waitcnt vmcnt(8); s_barrier` before reading
// buf[kt&3]. Column-slab XCD swizzle: XCD x owns n-panel x (B-panel 0.5MB ->
// L2-resident per XCD; A streams from L3 once per XCD). Bank-conflict fix:
// k-chunk XOR swizzle on global SOURCE + same involution on ds_read.
// DO_PAD=1 remaps output row m -> vpad row (b*LP + (m&2047) + PADF).
template<int DO_PAD>
__global__ __launch_bounds__(512) void gemm_split(const ushort* __restrict__ Ah,
                                                  const ushort* __restrict__ Al,
                                                  const ushort* __restrict__ Bh,
                                                  const ushort* __restrict__ Bl,
                                                  float* __restrict__ C)
{
    // [buf][plane][128 rows * 32 k]  plane: 0=Ah 1=Al 2=Bh 3=Bl
    __shared__ __align__(16) ushort lds[4][4][128 * 32];

    const int tid = threadIdx.x;
    const int w   = tid >> 6;
    const int l   = tid & 63;

    // Column-slab XCD swizzle: 256 blocks; xcd = blk&7 -> one n-panel per XCD.
    const int bn  = (blockIdx.x & 7) * 128;          // 8 n-tiles, one per XCD
    const int bm  = (blockIdx.x >> 3) * 128;         // 32 m-tiles across the XCD's CUs

    // --- staging: 512 threads x 16B = 8KB = one full plane per issue ---
    const int srow   = tid >> 2;                          // 0..127
    const int schunk = (tid & 3) ^ ((tid >> 3) & 3);      // pre-swizzled source chunk
    const ushort* gAh = Ah + (size_t)(bm + srow) * 1024 + schunk * 8;
    const ushort* gAl = Al + (size_t)(bm + srow) * 1024 + schunk * 8;
    const ushort* gBh = Bh + (size_t)(bn + srow) * 1024 + schunk * 8;
    const ushort* gBl = Bl + (size_t)(bn + srow) * 1024 + schunk * 8;
    const int ldst = tid * 8;                             // linear LDS dest (ushort)

    // --- fragment read params ---
    const int fr  = l & 15;                // row within 16x16 fragment
    const int fq  = l >> 4;                // k-chunk 0..3
    const int swz = (fr >> 1) & 3;         // (row>>1)&3, row-base multiple of 16
    const int rdo = (fq ^ swz) << 3;       // element offset of swizzled chunk
    const int wr  = w >> 2;                // 0..1  -> m offset wr*64
    const int wc  = w & 3;                 // 0..3  -> n offset wc*32

    f32x4 acc[4][2];
    #pragma unroll
    for (int mi = 0; mi < 4; ++mi)
        #pragma unroll
        for (int ni = 0; ni < 2; ++ni) acc[mi][ni] = (f32x4){0.f, 0.f, 0.f, 0.f};

    #define STAGE(buf, kt)                                        \
        do {                                                      \
            const size_t ko_ = (size_t)(kt) * 32;                 \
            gll16(gAh + ko_, &lds[(buf)][0][ldst]);               \
            gll16(gAl + ko_, &lds[(buf)][1][ldst]);               \
            gll16(gBh + ko_, &lds[(buf)][2][ldst]);               \
            gll16(gBl + ko_, &lds[(buf)][3][ldst]);               \
        } while (0)

    // WAITBAR(N): my tile-(kt) loads retired (N younger stay in flight),
    // then barrier -> ALL waves' tile-(kt) loads are in LDS.
    #define WAITBAR(N) asm volatile("s_waitcnt vmcnt(" #N ")\n\ts_barrier" ::: "memory")

    #define COMPUTE(cur)                                                                   \
        do {                                                                               \
            bf16x8 ah[4], al[4];                                                           \
            _Pragma("unroll")                                                              \
            for (int mi = 0; mi < 4; ++mi) {                                               \
                const int row = wr * 64 + mi * 16 + fr;                                    \
                ah[mi] = *(const bf16x8*)&lds[(cur)][0][row * 32 + rdo];                   \
                al[mi] = *(const bf16x8*)&lds[(cur)][1][row * 32 + rdo];                   \
            }                                                                              \
            _Pragma("unroll")                                                              \
            for (int ni = 0; ni < 2; ++ni) {                                               \
                const int row = wc * 32 + ni * 16 + fr;                                    \
                bf16x8 bh = *(const bf16x8*)&lds[(cur)][2][row * 32 + rdo];                \
                bf16x8 bl = *(const bf16x8*)&lds[(cur)][3][row * 32 + rdo];                \
                _Pragma("unroll")                                                          \
                for (int mi = 0; mi < 4; ++mi)                                             \
                    acc[mi][ni] = __builtin_amdgcn_mfma_f32_16x16x32_bf16(ah[mi], bh, acc[mi][ni], 0, 0, 0); \
                _Pragma("unroll")                                                          \
                for (int mi = 0; mi < 4; ++mi)                                             \
                    acc[mi][ni] = __builtin_amdgcn_mfma_f32_16x16x32_bf16(al[mi], bh, acc[mi][ni], 0, 0, 0); \
                _Pragma("unroll")                                                          \
                for (int mi = 0; mi < 4; ++mi)                                             \
                    acc[mi][ni] = __builtin_amdgcn_mfma_f32_16x16x32_bf16(ah[mi], bl, acc[mi][ni], 0, 0, 0); \
            }                                                                              \
        } while (0)

    STAGE(0, 0);
    STAGE(1, 1);
    STAGE(2, 2);

    for (int kt = 0; kt < 29; ++kt) {
        WAITBAR(8);
        STAGE((kt + 3) & 3, kt + 3);
        COMPUTE(kt & 3);
    }
    WAITBAR(8); COMPUTE(1);   // kt=29
    WAITBAR(4); COMPUTE(2);   // kt=30
    WAITBAR(0); COMPUTE(3);   // kt=31

    #undef STAGE
    #undef WAITBAR
    #undef COMPUTE

    // epilogue: C/D layout col=lane&15, row=(lane>>4)*4+reg  [m89/m91]
    #pragma unroll
    for (int mi = 0; mi < 4; ++mi) {
        #pragma unroll
        for (int ni = 0; ni < 2; ++ni) {
            const int col = bn + wc * 32 + ni * 16 + fr;
            #pragma unroll
            for (int j = 0; j < 4; ++j) {
                const int m = bm + wr * 64 + mi * 16 + fq * 4 + j;
                const size_t row = DO_PAD ? ((size_t)(m >> 11) * LP + (m & (L_SEQ - 1)) + PADF)
                                          : (size_t)m;
                C[row * 1024 + col] = acc[mi][ni][j];
            }
        }
    }
}

// ---------------------------------------------------------------------------
// gauss_conv_split: att[b,q,d] = sum_{delta=-71..56} w[h][delta]*vpad[b,q+delta,d]
// (delta=-72 term <= 5e-16, dropped). Block = 64 d-cols x 128 q-rows; stages
// 256 rows x 64 floats (64KB) in LDS once; each thread owns one d-column and
// 32 q-accumulators, sliding a 47-register window per 16-delta chunk.
// Emits bf16 hi/lo planes directly.
__global__ __launch_bounds__(256) void gauss_conv_split(const float* __restrict__ vpad,
                                                        ushort* __restrict__ Oh,
                                                        ushort* __restrict__ Ol)
{
    __shared__ __align__(16) float xs[256 * 64];   // [row][d] 64KB
    __shared__ float wt[128];                      // delta = j - 71

    const int tid = threadIdx.x;
    const int d0  = blockIdx.x * 64;
    const int q0  = blockIdx.y * 128;
    const int b   = blockIdx.z;
    const int h   = blockIdx.x >> 1;               // 64-wide d block => single head

    if (tid < 128) {
        const float sig = (float)(1 << (h & 3));   // std 1,2,4,8 ; offset = -std
        const float t = ((float)(tid - 71) + sig) / sig;
        wt[tid] = (0.39894228040143267794f / sig) * expf(-0.5f * t * t);
    }

    // stage rows [q0-71, q0+184] x [d0, d0+64)
    const float* src = vpad + ((size_t)b * LP + (PADF - 71) + q0) * 1024 + d0;
    #pragma unroll
    for (int p = 0; p < 16; ++p) {
        const int f   = p * 256 + tid;             // float4 index
        const int row = f >> 4;
        const int c4  = (f & 15) * 4;
        gll16(src + (size_t)row * 1024 + c4, &xs[f * 4]);
    }
    __syncthreads();

    const int d     = tid & 63;
    const int qbase = (tid >> 6) * 32;

    float acc[32];
    #pragma unroll
    for (int qq = 0; qq < 32; ++qq) acc[qq] = 0.f;

    #pragma unroll 1
    for (int c = 0; c < 8; ++c) {
        float xw[47];
        const float* xp = &xs[(qbase + c * 16) * 64 + d];
        #pragma unroll
        for (int j = 0; j < 47; ++j) xw[j] = xp[j * 64];
        #pragma unroll
        for (int dd = 0; dd < 16; ++dd) {
            const float wv = wt[c * 16 + dd];      // block-uniform broadcast
            #pragma unroll
            for (int qq = 0; qq < 32; ++qq)
                acc[qq] = fmaf(wv, xw[dd + qq], acc[qq]);
        }
    }

    ushort* oh = Oh + ((size_t)b * L_SEQ + q0 + qbase) * 1024 + d0 + d;
    ushort* ol = Ol + ((size_t)b * L_SEQ + q0 + qbase) * 1024 + d0 + d;
    #pragma unroll
    for (int qq = 0; qq < 32; ++qq) {
        const ushort hv = bf16_hi(acc[qq]);
        oh[(size_t)qq * 1024] = hv;
        ol[(size_t)qq * 1024] = bf16_hi(acc[qq] - bf16_back(hv));
    }
}

// ---------------------------------------------------------------------------
extern "C" void kernel_launch(void* const* d_in, const int* in_sizes, int n_in,
                              void* d_out, int out_size, void* d_ws, size_t ws_size,
                              hipStream_t stream)
{
    const float* values = (const float*)d_in[0];   // [B,L,D]
    const float* w_in   = (const float*)d_in[1];   // [D,D]
    const float* w_out  = (const float*)d_in[2];   // [D,D]
    float* out = (float*)d_out;                    // [B,L,D]

    // workspace layout (43.5 MB total)
    float*  vpad = (float*)d_ws;                                  // [B][LP][D] fp32
    ushort* Ph  = (ushort*)(vpad + (size_t)B_SZ * LP * D_MODEL);  // [4096][1024] bf16 hi
    ushort* Pl  = Ph  + (size_t)4096 * 1024;                      // lo
    ushort* Wh  = Pl  + (size_t)4096 * 1024;                      // w_in hi
    ushort* Wl  = Wh  + (size_t)1024 * 1024;                      // w_in lo
    ushort* W2h = Wl  + (size_t)1024 * 1024;                      // w_out hi
    ushort* W2l = W2h + (size_t)1024 * 1024;                      // w_out lo

    // 1) one prep launch: zero pads + split values/w_in/w_out into hi/lo planes
    prep<<<dim3(384 + 4096 + 1024 + 1024), dim3(256), 0, stream>>>(
        values, w_in, w_out, Ph, Pl, Wh, Wl, W2h, W2l, vpad);

    // 2) v = values @ w_in^T  (into padded fp32 buffer)
    gemm_split<1><<<dim3(256), dim3(512), 0, stream>>>(Ph, Pl, Wh, Wl, vpad);

    // 3) Gaussian conv -> att, emitted as bf16 hi/lo planes (reuses Ph/Pl)
    dim3 cgrid(D_MODEL / 64, L_SEQ / 128, B_SZ);   // 16 x 16 x 2 = 512 blocks
    gauss_conv_split<<<cgrid, dim3(256), 0, stream>>>(vpad, Ph, Pl);

    // 4) out = att @ w_out^T
    gemm_split<0><<<dim3(256), dim3(512), 0, stream>>>(Ph, Pl, W2h, W2l, out);
}